// Round 8
// baseline (393.494 us; speedup 1.0000x reference)
//
#include <hip/hip_runtime.h>
#include <hip/hip_bf16.h>

// MultiHeadSelfAttention: B=4, S=2048, D=1024, H=16, depth=64, eval mode.
// Inputs/outputs fp32 (per reference); internal compute bf16 MFMA + fp32 acc.
//
// Pipeline:
//   0) convert x fp32 -> xb bf16
//   1) transpose+convert weights -> WT bf16 (qkv concat, [3072][1024]), WoT
//   2) GEMM mode0 (m97-style global_load_lds): xb @ [Wq|Wk|Wv] + bias ->
//      Q(*0.125*log2e,[B,H,S,64]), K([B,H,S,64]), V^T -> d_out[0,16M)
//   3) flash attention v6 (static-max exp2 softmax) -> O bf16 (d_out[16M,32M))
//   4) GEMM mode1: O @ Wo + bo + x(fp32 residual) -> Tmp fp32 [8192][1024]
//   5) layernorm(Tmp)*gamma+beta -> out fp32 (overwrites all of d_out)
//
// Flash history (counters):
//   v2 (r4): persistent s[2][8] @(256,3) -> spill, 1.15 GB phantom writes.
//   v3 (r5): LDS K/V + persistent prefetch regs -> 443 MB phantom writes.
//   v4 (r6): direct-global K/V -> ideal traffic but latency-bound (479 us).
//   v5 (r7): transient-reg LDS staging -> 146 us, W=16MB F=40MB. Confirmed.
//   v6: + static-max softmax (P = 2^s, no max tracking: scores O(+-10) vs
//       exp2 range +-127 => ratios exact), l deferred to epilogue. Cuts the
//       ~80 VALU ops/qs-kt of max/alpha/rescale bookkeeping (r7: VALU 38% >>
//       Mfma 20%).
//
// Workspace (56 MB total):
//   [0,        16777216)  xb  bf16 [8192][1024]   (dead after GEMM0)
//   [16777216, 23068672)  WT  bf16 [3072][1024]   (dead after GEMM0)
//   [23068672, 39845888)  Q   bf16                (dead after flash)
//   [39845888, 56623104)  K   bf16                (dead after flash)
//   [56623104, 58720256)  WoT bf16 [1024][1024]   (needed by GEMM1 -> placed last)
//   Tmp fp32 [0, 33554432) aliases xb+WT+Q-prefix (all dead when GEMM1 runs)

typedef __bf16 bf16;
typedef __bf16 bf16x4 __attribute__((ext_vector_type(4)));
typedef __bf16 bf16x8 __attribute__((ext_vector_type(8)));
typedef float floatx4 __attribute__((ext_vector_type(4)));

#define MFMA16(a, b, c) __builtin_amdgcn_mfma_f32_16x16x32_bf16((a), (b), (c), 0, 0, 0)

// async global->LDS, 16B/lane; lds dest must be wave-uniform (HW scatters +lane*16)
__device__ __forceinline__ void gl_lds16(const bf16* g, bf16* l) {
    __builtin_amdgcn_global_load_lds(
        (const __attribute__((address_space(1))) void*)g,
        (__attribute__((address_space(3))) void*)l, 16, 0, 0);
}

// ---------------------------------------------------------------------------
// 0) fp32 -> bf16 convert (4 elems/thread)
__global__ __launch_bounds__(256) void convert_kernel(
    const float* __restrict__ x, bf16* __restrict__ xb)
{
    const int i = blockIdx.x * 256 + threadIdx.x;
    const float4 v = ((const float4*)x)[i];
    bf16x4 r;
    r[0] = (bf16)v.x; r[1] = (bf16)v.y; r[2] = (bf16)v.z; r[3] = (bf16)v.w;
    ((bf16x4*)xb)[i] = r;
}

// ---------------------------------------------------------------------------
// 1) 32x32 tiled transpose+convert: dst[n][k] = (bf16)src[k][n]; z picks W.
__global__ __launch_bounds__(256) void transpose_kernel(
    const float* __restrict__ Wq, const float* __restrict__ Wk,
    const float* __restrict__ Wv, const float* __restrict__ Wo,
    bf16* __restrict__ WT, bf16* __restrict__ WoT)
{
    __shared__ float tile[32][33];
    const int z = blockIdx.z;
    const float* src = (z == 0) ? Wq : (z == 1) ? Wk : (z == 2) ? Wv : Wo;
    bf16* dst = (z < 3) ? (WT + (long)z * 1024 * 1024) : WoT;
    const int n0 = blockIdx.x * 32, k0 = blockIdx.y * 32;
    const int tx = threadIdx.x & 31, ty = threadIdx.x >> 5;  // 8 rows x 32 cols
#pragma unroll
    for (int i = 0; i < 32; i += 8)
        tile[ty + i][tx] = src[(long)(k0 + ty + i) * 1024 + n0 + tx];
    __syncthreads();
#pragma unroll
    for (int i = 0; i < 32; i += 8)
        dst[(long)(n0 + ty + i) * 1024 + k0 + tx] = (bf16)tile[tx][ty + i];
}

// ---------------------------------------------------------------------------
// 2/4) GEMM C[M x N] = A[M x K] * Bt[N x K]^T, 128x128x32 tiles, 4 waves,
// m97-style: global_load_lds width-16 into UNPADDED LDS (64 B rows; b128
// fragment reads are conflict-minimal), 2-barrier K-loop, no staging regs.
// MODE 0: N=3072, epilogue scatters to Q (*0.125*log2e folded), K, Vt w/ bias.
// MODE 1: N=1024, epilogue Tmp = C + bias + X (fp32 residual), fp32 out.
template <int MODE>
__global__ __launch_bounds__(256, 2) void gemm_kernel(
    const bf16* __restrict__ A, const bf16* __restrict__ Bt,
    const float* __restrict__ b0, const float* __restrict__ b1,
    const float* __restrict__ b2, const float* __restrict__ X,
    bf16* __restrict__ Qo, bf16* __restrict__ Ko, bf16* __restrict__ Vto,
    float* __restrict__ Tmp, int N, int K)
{
    __shared__ __align__(16) bf16 As[128 * 32];  // 8 KB, unpadded (async dest)
    __shared__ __align__(16) bf16 Bs[128 * 32];
    const int t = threadIdx.x;
    const int lane = t & 63;
    const int w = t >> 6;
    const int wm = w >> 1, wn = w & 1;  // 2x2 waves -> 64x64 each
    const int g = lane >> 4, c = lane & 15;
    const int bm = blockIdx.y * 128;
    const int bn = blockIdx.x * 128;

    // async staging: wave w owns rows [w*32, w*32+32) of both tiles;
    // 2 calls per tile, lane i -> row chunk*16 + (i>>2), col (i&3)*8.
    const int srow = lane >> 2, scol = (lane & 3) * 8;
    const bf16* Ag0 = A + (long)(bm + w * 32 + srow) * K + scol;
    const bf16* Ag1 = A + (long)(bm + w * 32 + 16 + srow) * K + scol;
    const bf16* Bg0 = Bt + (long)(bn + w * 32 + srow) * K + scol;
    const bf16* Bg1 = Bt + (long)(bn + w * 32 + 16 + srow) * K + scol;
    bf16* Al0 = &As[(w * 32) * 32];      // wave-uniform LDS bases
    bf16* Al1 = &As[(w * 32 + 16) * 32];
    bf16* Bl0 = &Bs[(w * 32) * 32];
    bf16* Bl1 = &Bs[(w * 32 + 16) * 32];

    floatx4 acc[4][4];
#pragma unroll
    for (int i = 0; i < 4; ++i)
#pragma unroll
        for (int j = 0; j < 4; ++j) acc[i][j] = floatx4{0.f, 0.f, 0.f, 0.f};

    for (int k0 = 0; k0 < K; k0 += 32) {
        __syncthreads();  // previous iteration's fragment reads done
        gl_lds16(Ag0 + k0, Al0);
        gl_lds16(Ag1 + k0, Al1);
        gl_lds16(Bg0 + k0, Bl0);
        gl_lds16(Bg1 + k0, Bl1);
        __syncthreads();  // drains vmcnt(0): staged data visible
        bf16x8 af[4], bfv[4];
#pragma unroll
        for (int i = 0; i < 4; ++i)
            af[i] = *(const bf16x8*)&As[(wm * 64 + i * 16 + c) * 32 + g * 8];
#pragma unroll
        for (int j = 0; j < 4; ++j)
            bfv[j] = *(const bf16x8*)&Bs[(wn * 64 + j * 16 + c) * 32 + g * 8];
#pragma unroll
        for (int i = 0; i < 4; ++i)
#pragma unroll
            for (int j = 0; j < 4; ++j)
                acc[i][j] = MFMA16(af[i], bfv[j], acc[i][j]);
    }

    // Epilogue. C/D layout: col = c (lane&15), row = g*4 + reg.
    if (MODE == 0) {
#pragma unroll
        for (int j = 0; j < 4; ++j) {
            const int col = bn + wn * 64 + j * 16 + c;  // 0..3071
            const int sec = col >> 10;                  // 0=Q 1=K 2=V (uniform per j)
            const int nn = col & 1023;
            const int h = nn >> 6, dd = nn & 63;
            const float* bp = (sec == 0) ? b0 : (sec == 1) ? b1 : b2;
            const float bias = bp[nn];
#pragma unroll
            for (int i = 0; i < 4; ++i) {
                const int r0 = bm + wm * 64 + i * 16 + g * 4;
                if (sec == 2) {
                    bf16x4 pack;
#pragma unroll
                    for (int reg = 0; reg < 4; ++reg)
                        pack[reg] = (bf16)(acc[i][j][reg] + bias);
                    const int b_ = r0 >> 11, sr = r0 & 2047;  // r0 % 4 == 0, no 2048-cross
                    *(bf16x4*)&Vto[((long)(b_ * 16 + h) * 64 + dd) * 2048 + sr] = pack;
                } else {
#pragma unroll
                    for (int reg = 0; reg < 4; ++reg) {
                        const int r = r0 + reg;
                        const int b_ = r >> 11, sr = r & 2047;
                        const float v = acc[i][j][reg] + bias;
                        if (sec == 0)  // fold (1/8)*log2(e): softmax runs in exp2 domain
                            Qo[((long)(b_ * 16 + h) * 2048 + sr) * 64 + dd] =
                                (bf16)(v * 0.18033688011112042f);
                        else
                            Ko[((long)(b_ * 16 + h) * 2048 + sr) * 64 + dd] = (bf16)v;
                    }
                }
            }
        }
    } else {
#pragma unroll
        for (int j = 0; j < 4; ++j) {
            const int col = bn + wn * 64 + j * 16 + c;
            const float bias = b0[col];
#pragma unroll
            for (int i = 0; i < 4; ++i) {
#pragma unroll
                for (int reg = 0; reg < 4; ++reg) {
                    const int r = bm + wm * 64 + i * 16 + g * 4 + reg;
                    Tmp[(long)r * N + col] =
                        acc[i][j][reg] + bias + X[(long)r * N + col];
                }
            }
        }
    }
}

// ---------------------------------------------------------------------------
// 3) Flash attention v6: transposed-S, STATIC-MAX exp2 softmax (no max
// tracking, no O rescale, l deferred to epilogue), transient-reg LDS staging.
// Grid (64 bh, 16 qt): head-major pins each head to one XCD. 4 waves/block,
// 32 q-rows each, q-tiles sequential (only s[8] live -> no spill).
__global__ __launch_bounds__(256, 2) void flash_kernel(
    const bf16* __restrict__ Q, const bf16* __restrict__ Kc,
    const bf16* __restrict__ Vt, bf16* __restrict__ O)
{
    constexpr int KSTR = 72;   // 64 + 8 pad (bf16)
    constexpr int VSTR = 136;  // 128 + 8 pad
    constexpr int PSTR = 136;
    __shared__ __align__(16) bf16 Ks[128 * KSTR];    // 18432 B
    __shared__ __align__(16) bf16 Vs[64 * VSTR];     // 17408 B
    __shared__ __align__(16) bf16 Pl[4 * 16 * PSTR]; // 17408 B (16 rows/wave)
    const int t = threadIdx.x;
    const int lane = t & 63;
    const int w = t >> 6;
    const int g = lane >> 4, c = lane & 15;
    const int bh = blockIdx.x;           // head-major: XCD-local K/V
    const int b_ = bh >> 4, h = bh & 15;
    const bf16* Qp = Q + (long)bh * 2048 * 64;
    const bf16* Kp = Kc + (long)bh * 2048 * 64;
    const bf16* Vp = Vt + (long)bh * 64 * 2048;
    const int q0 = blockIdx.y * 128 + w * 32;
    bf16* Pw = Pl + w * 16 * PSTR;  // wave-private

    // Q fragments (B operand: n = q = c, k(depth) = g*8+j), whole-loop regs
    bf16x8 qf[2][2];
#pragma unroll
    for (int qs = 0; qs < 2; ++qs)
#pragma unroll
        for (int p = 0; p < 2; ++p)
            qf[qs][p] = *(const bf16x8*)(Qp + (long)(q0 + qs * 16 + c) * 64 + p * 32 + g * 8);

    floatx4 la[2];  // deferred softmax denominator, kv in (reg, g) domains
    la[0] = floatx4{0.f, 0.f, 0.f, 0.f};
    la[1] = floatx4{0.f, 0.f, 0.f, 0.f};
    floatx4 o[2][4];
#pragma unroll
    for (int qs = 0; qs < 2; ++qs)
#pragma unroll
        for (int dd = 0; dd < 4; ++dd) o[qs][dd] = floatx4{0.f, 0.f, 0.f, 0.f};

    for (int kt = 0; kt < 16; ++kt) {
        __syncthreads();  // all waves done reading tiles of kt-1
        {   // transient staging: 8 uint4 live only inside this barrier pair
            uint4 kr[4], vr[4];
#pragma unroll
            for (int i = 0; i < 4; ++i) {
                const int idx = i * 256 + t;
                kr[i] = *(const uint4*)(Kp + (long)kt * 8192 + idx * 8);
                const int vd = idx >> 4, vsc = idx & 15;
                vr[i] = *(const uint4*)(Vp + (long)vd * 2048 + kt * 128 + vsc * 8);
            }
#pragma unroll
            for (int i = 0; i < 4; ++i) {
                const int idx = i * 256 + t;
                *(uint4*)&Ks[(idx >> 3) * KSTR + (idx & 7) * 8] = kr[i];
                *(uint4*)&Vs[(idx >> 4) * VSTR + (idx & 15) * 8] = vr[i];
            }
        }
        __syncthreads();

        // q-tiles sequential: only s[8] (32 VGPRs) live at a time.
#pragma unroll
        for (int qs = 0; qs < 2; ++qs) {
            // S^T = K·Q^T: A = K-frag (m = kv = c), B = Q-frag (n = q = c).
            // C layout: row g*4+r = kv-in-tile, col c = q.
            floatx4 s[8];
#pragma unroll
            for (int ks = 0; ks < 8; ++ks) {
                bf16x8 kf0 = *(const bf16x8*)&Ks[(ks * 16 + c) * KSTR + g * 8];
                bf16x8 kf1 = *(const bf16x8*)&Ks[(ks * 16 + c) * KSTR + 32 + g * 8];
                floatx4 z = floatx4{0.f, 0.f, 0.f, 0.f};
                z = MFMA16(kf0, qf[qs][0], z);
                z = MFMA16(kf1, qf[qs][1], z);
                s[ks] = z;
            }
            // static-max: P = 2^s directly (s is O(+-10); exp2 range +-127).
            floatx4 a4 = floatx4{0.f, 0.f, 0.f, 0.f};
#pragma unroll
            for (int ks = 0; ks < 8; ++ks) {
#pragma unroll
                for (int r = 0; r < 4; ++r)
                    s[ks][r] = __builtin_amdgcn_exp2f(s[ks][r]);
                a4 += s[ks];
            }
            la[qs] += a4;  // denominator deferred; no alpha, no O rescale
            // P -> LDS, packed b64 (4 consecutive kv per lane: k = ks*16+g*4)
#pragma unroll
            for (int ks = 0; ks < 8; ++ks) {
                bf16x4 pk;
#pragma unroll
                for (int r = 0; r < 4; ++r) pk[r] = (bf16)s[ks][r];
                *(bf16x4*)&Pw[c * PSTR + ks * 16 + g * 4] = pk;
            }
            asm volatile("s_waitcnt lgkmcnt(0)" ::: "memory");  // P visible wave-wide
            // O += P·V: A = P[m=q=c][k=kv], B = V^T[n=d=c][k=kv] from LDS
#pragma unroll
            for (int kk = 0; kk < 4; ++kk) {
                bf16x8 pf = *(const bf16x8*)&Pw[c * PSTR + kk * 32 + g * 8];
#pragma unroll
                for (int dd = 0; dd < 4; ++dd) {
                    bf16x8 vf = *(const bf16x8*)&Vs[(dd * 16 + c) * VSTR + kk * 32 + g * 8];
                    o[qs][dd] = MFMA16(pf, vf, o[qs][dd]);
                }
            }
        }
    }

    // epilogue: reduce l (regs -> g-groups), transport to row domain, O/l.
#pragma unroll
    for (int qs = 0; qs < 2; ++qs) {
        float l = (la[qs][0] + la[qs][1]) + (la[qs][2] + la[qs][3]);
        l += __shfl_xor(l, 16, 64);
        l += __shfl_xor(l, 32, 64);  // all lanes: l for q = qs*16 + c
        float linv[4];
#pragma unroll
        for (int r = 0; r < 4; ++r) linv[r] = 1.0f / __shfl(l, g * 4 + r, 64);
#pragma unroll
        for (int dd = 0; dd < 4; ++dd)
#pragma unroll
            for (int r = 0; r < 4; ++r) {
                const float v = o[qs][dd][r] * linv[r];
                const int q = q0 + qs * 16 + g * 4 + r;
                O[((long)b_ * 2048 + q) * 1024 + h * 64 + dd * 16 + c] = (bf16)v;
            }
    }
}

// ---------------------------------------------------------------------------
// 5) LayerNorm over rows of Tmp (fp32), one block per row, fp32 out.
__global__ __launch_bounds__(256, 2) void ln_kernel(
    const float* __restrict__ Tmp, const float* __restrict__ gamma,
    const float* __restrict__ beta, float* __restrict__ out)
{
    const int row = blockIdx.x;
    const int t = threadIdx.x;
    const int lane = t & 63, w = t >> 6;
    const float4 v = ((const float4*)(Tmp + (long)row * 1024))[t];
    float s = v.x + v.y + v.z + v.w;
    float ss = v.x * v.x + v.y * v.y + v.z * v.z + v.w * v.w;
#pragma unroll
    for (int off = 1; off < 64; off <<= 1) {
        s += __shfl_xor(s, off, 64);
        ss += __shfl_xor(ss, off, 64);
    }
    __shared__ float sb[4], ssb[4];
    if (lane == 0) { sb[w] = s; ssb[w] = ss; }
    __syncthreads();
    s = sb[0] + sb[1] + sb[2] + sb[3];
    ss = ssb[0] + ssb[1] + ssb[2] + ssb[3];
    const float mu = s * (1.0f / 1024.0f);
    const float var = ss * (1.0f / 1024.0f) - mu * mu;
    const float inv = rsqrtf(var + 1e-6f);
    const float4 gm = ((const float4*)gamma)[t];
    const float4 bt = ((const float4*)beta)[t];
    float4 r;
    r.x = (v.x - mu) * inv * gm.x + bt.x;
    r.y = (v.y - mu) * inv * gm.y + bt.y;
    r.z = (v.z - mu) * inv * gm.z + bt.z;
    r.w = (v.w - mu) * inv * gm.w + bt.w;
    ((float4*)(out + (long)row * 1024))[t] = r;
}

// ---------------------------------------------------------------------------
extern "C" void kernel_launch(void* const* d_in, const int* in_sizes, int n_in,
                              void* d_out, int out_size, void* d_ws, size_t ws_size,
                              hipStream_t stream)
{
    const float* x     = (const float*)d_in[0];
    const float* Wq    = (const float*)d_in[1];
    const float* bq    = (const float*)d_in[2];
    const float* Wk    = (const float*)d_in[3];
    const float* bk    = (const float*)d_in[4];
    const float* Wv    = (const float*)d_in[5];
    const float* bv    = (const float*)d_in[6];
    const float* Wo    = (const float*)d_in[7];
    const float* bo    = (const float*)d_in[8];
    const float* gamma = (const float*)d_in[9];
    const float* beta  = (const float*)d_in[10];
    float* out = (float*)d_out;

    char* ws = (char*)d_ws;
    bf16* xb   = (bf16*)(ws);                   // [0, 16777216)
    bf16* WT   = (bf16*)(ws + 16777216);        // [16777216, 23068672)
    bf16* Qb   = (bf16*)(ws + 23068672);        // [23068672, 39845888)
    bf16* Kb   = (bf16*)(ws + 39845888);        // [39845888, 56623104)
    bf16* WoT  = (bf16*)(ws + 56623104);        // [56623104, 58720256)
    float* Tmp = (float*)(ws);                  // [0, 33554432) alias dead xb/WT/Q-prefix
    bf16* Vtb  = (bf16*)d_out;                  // V^T parks in d_out[0, 16M)
    bf16* Ob   = (bf16*)((char*)d_out + 16777216);  // O parks in d_out[16M, 32M)

    convert_kernel<<<8192, 256, 0, stream>>>(x, xb);
    transpose_kernel<<<dim3(32, 32, 4), 256, 0, stream>>>(Wq, Wk, Wv, Wo, WT, WoT);
    gemm_kernel<0><<<dim3(24, 64), 256, 0, stream>>>(
        xb, WT, bq, bk, bv, nullptr, Qb, Kb, Vtb, nullptr, 3072, 1024);
    flash_kernel<<<dim3(64, 16), 256, 0, stream>>>(Qb, Kb, Vtb, Ob);
    gemm_kernel<1><<<dim3(8, 64), 256, 0, stream>>>(
        Ob, WoT, bo, nullptr, nullptr, x, nullptr, nullptr, nullptr, Tmp, 1024, 1024);
    ln_kernel<<<8192, 256, 0, stream>>>(Tmp, gamma, beta, out);
}

// Round 10
// 343.789 us; speedup vs baseline: 1.1446x; 1.1446x over previous
//
#include <hip/hip_runtime.h>
#include <hip/hip_bf16.h>

// MultiHeadSelfAttention: B=4, S=2048, D=1024, H=16, depth=64, eval mode.
// Inputs/outputs fp32 (per reference); internal compute bf16 MFMA + fp32 acc.
//
// Pipeline:
//   0) convert x fp32 -> xb bf16
//   1) transpose+convert weights -> WT bf16 (qkv concat, [3072][1024]), WoT
//   2) GEMM mode0: xb @ [Wq|Wk|Wv] + bias -> Q(*0.125*log2e,[B,H,S,64]),
//      K([B,H,S,64]), V^T([B,H,64,S] -> d_out[0,16M))
//   3) flash attention v7 -> O bf16 (d_out[16M,32M))
//   4) GEMM mode1: O @ Wo + bo + x(fp32 residual) -> Tmp BF16 [8192][1024]
//   5) layernorm(Tmp)*gamma+beta -> out fp32 (overwrites all of d_out)
//
// Flash history (counters):
//   v2 (r4): s[2][8] @(256,3) -> 170-reg cap -> spill, 1.15 GB phantom writes.
//   v3 (r5): LDS K/V + persistent prefetch regs -> 443 MB phantom writes.
//   v4 (r6): direct-global K/V -> ideal traffic but latency-bound (479 us).
//   v5 (r7): transient-reg LDS staging, online softmax -> 146 us. PROVEN.
//   v6 (r8): static-max softmax -> SLOWER (181 us): VALU bookkeeping was
//            filling stalls; kernel is latency-bound, not VALU-bound. Reverted.
//   v7: v5 + merged q-tiles: one K-frag load feeds both q-tiles' QK MFMAs,
//       one V-frag load feeds both PV MFMAs (halves LDS reads 73->41 KB/kt,
//       2x independent MFMA per load, single lgkmcnt drain). Safe now under
//       (256,2): peak live ~140 regs < 256 cap (r4's failure was the cap).
//   (r9: same kernel, compile fix — GEMM1 call was missing the Vto nullptr.)
//
// Workspace (56 MB total):
//   [0,        16777216)  xb  bf16 [8192][1024]   (dead after GEMM0)
//   [16777216, 23068672)  WT  bf16 [3072][1024]   (dead after GEMM0)
//   [23068672, 39845888)  Q   bf16                (dead after flash)
//   [39845888, 56623104)  K   bf16                (dead after flash)
//   [56623104, 58720256)  WoT bf16 [1024][1024]   (needed by GEMM1 -> placed last)
//   Tmp bf16 [0, 16777216) aliases dead xb when GEMM1 runs

typedef __bf16 bf16;
typedef __bf16 bf16x4 __attribute__((ext_vector_type(4)));
typedef __bf16 bf16x8 __attribute__((ext_vector_type(8)));
typedef float floatx4 __attribute__((ext_vector_type(4)));

#define MFMA16(a, b, c) __builtin_amdgcn_mfma_f32_16x16x32_bf16((a), (b), (c), 0, 0, 0)

static __device__ __forceinline__ floatx4 vmax4(floatx4 a, floatx4 b) {
    floatx4 r;
    r[0] = fmaxf(a[0], b[0]); r[1] = fmaxf(a[1], b[1]);
    r[2] = fmaxf(a[2], b[2]); r[3] = fmaxf(a[3], b[3]);
    return r;
}

// ---------------------------------------------------------------------------
// 0) fp32 -> bf16 convert (4 elems/thread)
__global__ __launch_bounds__(256) void convert_kernel(
    const float* __restrict__ x, bf16* __restrict__ xb)
{
    const int i = blockIdx.x * 256 + threadIdx.x;
    const float4 v = ((const float4*)x)[i];
    bf16x4 r;
    r[0] = (bf16)v.x; r[1] = (bf16)v.y; r[2] = (bf16)v.z; r[3] = (bf16)v.w;
    ((bf16x4*)xb)[i] = r;
}

// ---------------------------------------------------------------------------
// 1) 32x32 tiled transpose+convert: dst[n][k] = (bf16)src[k][n]; z picks W.
__global__ __launch_bounds__(256) void transpose_kernel(
    const float* __restrict__ Wq, const float* __restrict__ Wk,
    const float* __restrict__ Wv, const float* __restrict__ Wo,
    bf16* __restrict__ WT, bf16* __restrict__ WoT)
{
    __shared__ float tile[32][33];
    const int z = blockIdx.z;
    const float* src = (z == 0) ? Wq : (z == 1) ? Wk : (z == 2) ? Wv : Wo;
    bf16* dst = (z < 3) ? (WT + (long)z * 1024 * 1024) : WoT;
    const int n0 = blockIdx.x * 32, k0 = blockIdx.y * 32;
    const int tx = threadIdx.x & 31, ty = threadIdx.x >> 5;  // 8 rows x 32 cols
#pragma unroll
    for (int i = 0; i < 32; i += 8)
        tile[ty + i][tx] = src[(long)(k0 + ty + i) * 1024 + n0 + tx];
    __syncthreads();
#pragma unroll
    for (int i = 0; i < 32; i += 8)
        dst[(long)(n0 + ty + i) * 1024 + k0 + tx] = (bf16)tile[tx][ty + i];
}

// ---------------------------------------------------------------------------
// 2/4) GEMM C[M x N] = A[M x K] * Bt[N x K]^T, 128x128x32 tiles, 4 waves
// (r7-proven: padded LDS, uint4 reg staging+prefetch).
// MODE 0: N=3072, epilogue scatters to Q (*0.125*log2e folded), K, Vt w/ bias.
// MODE 1: N=1024, epilogue Tmp = bf16(C + bias + X residual).
template <int MODE>
__global__ __launch_bounds__(256, 2) void gemm_kernel(
    const bf16* __restrict__ A, const bf16* __restrict__ Bt,
    const float* __restrict__ b0, const float* __restrict__ b1,
    const float* __restrict__ b2, const float* __restrict__ X,
    bf16* __restrict__ Qo, bf16* __restrict__ Ko, bf16* __restrict__ Vto,
    bf16* __restrict__ Tmpb, int N, int K)
{
    constexpr int LDT = 40;  // 32 + 8 pad: keeps 16B alignment, breaks bank conflicts
    __shared__ __align__(16) bf16 As[128 * LDT];
    __shared__ __align__(16) bf16 Bs[128 * LDT];
    const int t = threadIdx.x;
    const int lane = t & 63;
    const int w = t >> 6;
    const int wm = w >> 1, wn = w & 1;  // 2x2 waves -> 64x64 each
    const int g = lane >> 4, c = lane & 15;
    const int bm = blockIdx.y * 128;
    const int bn = blockIdx.x * 128;

    const int srow = t >> 2;        // 0..63
    const int scol = (t & 3) * 8;   // element offset (8 bf16 = 16B)

    floatx4 acc[4][4];
#pragma unroll
    for (int i = 0; i < 4; ++i)
#pragma unroll
        for (int j = 0; j < 4; ++j) acc[i][j] = floatx4{0.f, 0.f, 0.f, 0.f};

    const bf16* Ap0 = A + (long)(bm + srow) * K + scol;
    const bf16* Ap1 = A + (long)(bm + 64 + srow) * K + scol;
    const bf16* Bp0 = Bt + (long)(bn + srow) * K + scol;
    const bf16* Bp1 = Bt + (long)(bn + 64 + srow) * K + scol;

    uint4 a0 = *(const uint4*)(Ap0);
    uint4 a1 = *(const uint4*)(Ap1);
    uint4 q0 = *(const uint4*)(Bp0);
    uint4 q1 = *(const uint4*)(Bp1);

    for (int k0 = 0; k0 < K; k0 += 32) {
        __syncthreads();  // previous iteration's fragment reads are done
        *(uint4*)&As[srow * LDT + scol] = a0;
        *(uint4*)&As[(64 + srow) * LDT + scol] = a1;
        *(uint4*)&Bs[srow * LDT + scol] = q0;
        *(uint4*)&Bs[(64 + srow) * LDT + scol] = q1;
        __syncthreads();
        if (k0 + 32 < K) {  // prefetch next K-slab; overlaps MFMA below
            a0 = *(const uint4*)(Ap0 + k0 + 32);
            a1 = *(const uint4*)(Ap1 + k0 + 32);
            q0 = *(const uint4*)(Bp0 + k0 + 32);
            q1 = *(const uint4*)(Bp1 + k0 + 32);
        }
        bf16x8 af[4], bfv[4];
#pragma unroll
        for (int i = 0; i < 4; ++i)
            af[i] = *(const bf16x8*)&As[(wm * 64 + i * 16 + c) * LDT + g * 8];
#pragma unroll
        for (int j = 0; j < 4; ++j)
            bfv[j] = *(const bf16x8*)&Bs[(wn * 64 + j * 16 + c) * LDT + g * 8];
#pragma unroll
        for (int i = 0; i < 4; ++i)
#pragma unroll
            for (int j = 0; j < 4; ++j)
                acc[i][j] = MFMA16(af[i], bfv[j], acc[i][j]);
    }

    // Epilogue. C/D layout: col = c (lane&15), row = g*4 + reg.
    if (MODE == 0) {
#pragma unroll
        for (int j = 0; j < 4; ++j) {
            const int col = bn + wn * 64 + j * 16 + c;  // 0..3071
            const int sec = col >> 10;                  // 0=Q 1=K 2=V (uniform per j)
            const int nn = col & 1023;
            const int h = nn >> 6, dd = nn & 63;
            const float* bp = (sec == 0) ? b0 : (sec == 1) ? b1 : b2;
            const float bias = bp[nn];
#pragma unroll
            for (int i = 0; i < 4; ++i) {
                const int r0 = bm + wm * 64 + i * 16 + g * 4;
                if (sec == 2) {
                    bf16x4 pack;
#pragma unroll
                    for (int reg = 0; reg < 4; ++reg)
                        pack[reg] = (bf16)(acc[i][j][reg] + bias);
                    const int b_ = r0 >> 11, sr = r0 & 2047;  // r0 % 4 == 0, no 2048-cross
                    *(bf16x4*)&Vto[((long)(b_ * 16 + h) * 64 + dd) * 2048 + sr] = pack;
                } else {
#pragma unroll
                    for (int reg = 0; reg < 4; ++reg) {
                        const int r = r0 + reg;
                        const int b_ = r >> 11, sr = r & 2047;
                        const float v = acc[i][j][reg] + bias;
                        if (sec == 0)  // fold (1/8)*log2(e): softmax runs in exp2 domain
                            Qo[((long)(b_ * 16 + h) * 2048 + sr) * 64 + dd] =
                                (bf16)(v * 0.18033688011112042f);
                        else
                            Ko[((long)(b_ * 16 + h) * 2048 + sr) * 64 + dd] = (bf16)v;
                    }
                }
            }
        }
    } else {
#pragma unroll
        for (int j = 0; j < 4; ++j) {
            const int col = bn + wn * 64 + j * 16 + c;
            const float bias = b0[col];
#pragma unroll
            for (int i = 0; i < 4; ++i) {
#pragma unroll
                for (int reg = 0; reg < 4; ++reg) {
                    const int r = bm + wm * 64 + i * 16 + g * 4 + reg;
                    Tmpb[(long)r * N + col] =
                        (bf16)(acc[i][j][reg] + bias + X[(long)r * N + col]);
                }
            }
        }
    }
}

// ---------------------------------------------------------------------------
// 3) Flash attention v7: v5 (transposed-S, online exp2 softmax, transient-reg
// LDS staging) + merged q-tiles: s[2][8] live together so each K-fragment
// load feeds 2 QK MFMAs and each V-fragment load feeds 2 PV MFMAs (halves
// LDS reads), single lgkmcnt drain per kt. Grid (64 bh, 16 qt): head-major
// pins each head's blocks to one XCD. 4 waves/block, 32 q-rows each.
__global__ __launch_bounds__(256, 2) void flash_kernel(
    const bf16* __restrict__ Q, const bf16* __restrict__ Kc,
    const bf16* __restrict__ Vt, bf16* __restrict__ O)
{
    constexpr int KSTR = 72;   // 64 + 8 pad (bf16)
    constexpr int VSTR = 136;  // 128 + 8 pad
    constexpr int PSTR = 136;
    __shared__ __align__(16) bf16 Ks[128 * KSTR];    // 18432 B
    __shared__ __align__(16) bf16 Vs[64 * VSTR];     // 17408 B
    __shared__ __align__(16) bf16 Pl[4 * 32 * PSTR]; // 34816 B (32 rows/wave)
    const int t = threadIdx.x;
    const int lane = t & 63;
    const int w = t >> 6;
    const int g = lane >> 4, c = lane & 15;
    const int bh = blockIdx.x;           // head-major: XCD-local K/V
    const int b_ = bh >> 4, h = bh & 15;
    const bf16* Qp = Q + (long)bh * 2048 * 64;
    const bf16* Kp = Kc + (long)bh * 2048 * 64;
    const bf16* Vp = Vt + (long)bh * 64 * 2048;
    const int q0 = blockIdx.y * 128 + w * 32;
    bf16* Pw = Pl + w * 32 * PSTR;  // wave-private, 32 rows (16 per q-tile)

    // Q fragments (B operand: n = q = c, k(depth) = g*8+j), whole-loop regs
    bf16x8 qf[2][2];
#pragma unroll
    for (int qs = 0; qs < 2; ++qs)
#pragma unroll
        for (int p = 0; p < 2; ++p)
            qf[qs][p] = *(const bf16x8*)(Qp + (long)(q0 + qs * 16 + c) * 64 + p * 32 + g * 8);

    float m_c[2] = {-1e30f, -1e30f};  // per-lane: q = qs*16 + c (g-uniform)
    float l_c[2] = {0.f, 0.f};
    floatx4 o[2][4];
#pragma unroll
    for (int qs = 0; qs < 2; ++qs)
#pragma unroll
        for (int dd = 0; dd < 4; ++dd) o[qs][dd] = floatx4{0.f, 0.f, 0.f, 0.f};

    for (int kt = 0; kt < 16; ++kt) {
        __syncthreads();  // all waves done reading tiles of kt-1
        {   // transient staging: 8 uint4 live only inside this barrier pair
            uint4 kr[4], vr[4];
#pragma unroll
            for (int i = 0; i < 4; ++i) {
                const int idx = i * 256 + t;
                kr[i] = *(const uint4*)(Kp + (long)kt * 8192 + idx * 8);
                const int vd = idx >> 4, vsc = idx & 15;
                vr[i] = *(const uint4*)(Vp + (long)vd * 2048 + kt * 128 + vsc * 8);
            }
#pragma unroll
            for (int i = 0; i < 4; ++i) {
                const int idx = i * 256 + t;
                *(uint4*)&Ks[(idx >> 3) * KSTR + (idx & 7) * 8] = kr[i];
                *(uint4*)&Vs[(idx >> 4) * VSTR + (idx & 15) * 8] = vr[i];
            }
        }
        __syncthreads();

        // S^T = K·Q^T for BOTH q-tiles off one K-frag load.
        // C layout: row g*4+r = kv-in-tile, col c = q.
        floatx4 s[2][8];
#pragma unroll
        for (int ks = 0; ks < 8; ++ks) {
            bf16x8 kf0 = *(const bf16x8*)&Ks[(ks * 16 + c) * KSTR + g * 8];
            bf16x8 kf1 = *(const bf16x8*)&Ks[(ks * 16 + c) * KSTR + 32 + g * 8];
#pragma unroll
            for (int qs = 0; qs < 2; ++qs) {
                floatx4 z = floatx4{0.f, 0.f, 0.f, 0.f};
                z = MFMA16(kf0, qf[qs][0], z);
                z = MFMA16(kf1, qf[qs][1], z);
                s[qs][ks] = z;
            }
        }

        // online softmax per q-tile (v5-proven), P -> wave-private LDS rows
#pragma unroll
        for (int qs = 0; qs < 2; ++qs) {
            floatx4 t0 = vmax4(s[qs][0], s[qs][1]);
            floatx4 t1 = vmax4(s[qs][2], s[qs][3]);
            floatx4 t2 = vmax4(s[qs][4], s[qs][5]);
            floatx4 t3 = vmax4(s[qs][6], s[qs][7]);
            t0 = vmax4(vmax4(t0, t1), vmax4(t2, t3));
            float mx = fmaxf(fmaxf(t0[0], t0[1]), fmaxf(t0[2], t0[3]));
            mx = fmaxf(mx, __shfl_xor(mx, 16, 64));
            mx = fmaxf(mx, __shfl_xor(mx, 32, 64));
            const float mn = fmaxf(m_c[qs], mx);
            const float al = __builtin_amdgcn_exp2f(m_c[qs] - mn);
            m_c[qs] = mn;
            floatx4 a4 = floatx4{0.f, 0.f, 0.f, 0.f};
#pragma unroll
            for (int ks = 0; ks < 8; ++ks) {
#pragma unroll
                for (int r = 0; r < 4; ++r)
                    s[qs][ks][r] = __builtin_amdgcn_exp2f(s[qs][ks][r] - mn);
                a4 += s[qs][ks];
            }
            float rs = (a4[0] + a4[1]) + (a4[2] + a4[3]);
            rs += __shfl_xor(rs, 16, 64);
            rs += __shfl_xor(rs, 32, 64);
            l_c[qs] = l_c[qs] * al + rs;
            float al_r[4];
#pragma unroll
            for (int r = 0; r < 4; ++r) al_r[r] = __shfl(al, g * 4 + r, 64);
#pragma unroll
            for (int dd = 0; dd < 4; ++dd)
#pragma unroll
                for (int r = 0; r < 4; ++r) o[qs][dd][r] *= al_r[r];
#pragma unroll
            for (int ks = 0; ks < 8; ++ks) {
                bf16x4 pk;
#pragma unroll
                for (int r = 0; r < 4; ++r) pk[r] = (bf16)s[qs][ks][r];
                *(bf16x4*)&Pw[(qs * 16 + c) * PSTR + ks * 16 + g * 4] = pk;
            }
        }
        asm volatile("s_waitcnt lgkmcnt(0)" ::: "memory");  // both P tiles visible
        // O += P·V for BOTH q-tiles off one V-frag load.
#pragma unroll
        for (int kk = 0; kk < 4; ++kk) {
            bf16x8 pf0 = *(const bf16x8*)&Pw[(0 + c) * PSTR + kk * 32 + g * 8];
            bf16x8 pf1 = *(const bf16x8*)&Pw[(16 + c) * PSTR + kk * 32 + g * 8];
#pragma unroll
            for (int dd = 0; dd < 4; ++dd) {
                bf16x8 vf = *(const bf16x8*)&Vs[(dd * 16 + c) * VSTR + kk * 32 + g * 8];
                o[0][dd] = MFMA16(pf0, vf, o[0][dd]);
                o[1][dd] = MFMA16(pf1, vf, o[1][dd]);
            }
        }
    }

    // epilogue: transport l to row domain, O/l, store [B,S,1024] (merge heads)
#pragma unroll
    for (int qs = 0; qs < 2; ++qs) {
        float linv[4];
#pragma unroll
        for (int r = 0; r < 4; ++r) linv[r] = 1.0f / __shfl(l_c[qs], g * 4 + r, 64);
#pragma unroll
        for (int dd = 0; dd < 4; ++dd)
#pragma unroll
            for (int r = 0; r < 4; ++r) {
                const float v = o[qs][dd][r] * linv[r];
                const int q = q0 + qs * 16 + g * 4 + r;
                O[((long)b_ * 2048 + q) * 1024 + h * 64 + dd * 16 + c] = (bf16)v;
            }
    }
}

// ---------------------------------------------------------------------------
// 5) LayerNorm over rows of Tmp (bf16), one block per row, fp32 out.
__global__ __launch_bounds__(256, 2) void ln_kernel(
    const bf16* __restrict__ Tmp, const float* __restrict__ gamma,
    const float* __restrict__ beta, float* __restrict__ out)
{
    const int row = blockIdx.x;
    const int t = threadIdx.x;
    const int lane = t & 63, w = t >> 6;
    const bf16x4 vb = ((const bf16x4*)(Tmp + (long)row * 1024))[t];
    const float xv[4] = {(float)vb[0], (float)vb[1], (float)vb[2], (float)vb[3]};
    float s = xv[0] + xv[1] + xv[2] + xv[3];
    float ss = xv[0] * xv[0] + xv[1] * xv[1] + xv[2] * xv[2] + xv[3] * xv[3];
#pragma unroll
    for (int off = 1; off < 64; off <<= 1) {
        s += __shfl_xor(s, off, 64);
        ss += __shfl_xor(ss, off, 64);
    }
    __shared__ float sb[4], ssb[4];
    if (lane == 0) { sb[w] = s; ssb[w] = ss; }
    __syncthreads();
    s = sb[0] + sb[1] + sb[2] + sb[3];
    ss = ssb[0] + ssb[1] + ssb[2] + ssb[3];
    const float mu = s * (1.0f / 1024.0f);
    const float var = ss * (1.0f / 1024.0f) - mu * mu;
    const float inv = rsqrtf(var + 1e-6f);
    const float4 gm = ((const float4*)gamma)[t];
    const float4 bt = ((const float4*)beta)[t];
    float4 r;
    r.x = (xv[0] - mu) * inv * gm.x + bt.x;
    r.y = (xv[1] - mu) * inv * gm.y + bt.y;
    r.z = (xv[2] - mu) * inv * gm.z + bt.z;
    r.w = (xv[3] - mu) * inv * gm.w + bt.w;
    ((float4*)(out + (long)row * 1024))[t] = r;
}

// ---------------------------------------------------------------------------
extern "C" void kernel_launch(void* const* d_in, const int* in_sizes, int n_in,
                              void* d_out, int out_size, void* d_ws, size_t ws_size,
                              hipStream_t stream)
{
    const float* x     = (const float*)d_in[0];
    const float* Wq    = (const float*)d_in[1];
    const float* bq    = (const float*)d_in[2];
    const float* Wk    = (const float*)d_in[3];
    const float* bk    = (const float*)d_in[4];
    const float* Wv    = (const float*)d_in[5];
    const float* bv    = (const float*)d_in[6];
    const float* Wo    = (const float*)d_in[7];
    const float* bo    = (const float*)d_in[8];
    const float* gamma = (const float*)d_in[9];
    const float* beta  = (const float*)d_in[10];
    float* out = (float*)d_out;

    char* ws = (char*)d_ws;
    bf16* xb   = (bf16*)(ws);                   // [0, 16777216)
    bf16* WT   = (bf16*)(ws + 16777216);        // [16777216, 23068672)
    bf16* Qb   = (bf16*)(ws + 23068672);        // [23068672, 39845888)
    bf16* Kb   = (bf16*)(ws + 39845888);        // [39845888, 56623104)
    bf16* WoT  = (bf16*)(ws + 56623104);        // [56623104, 58720256)
    bf16* Tmpb = (bf16*)(ws);                   // [0, 16777216) alias dead xb
    bf16* Vtb  = (bf16*)d_out;                  // V^T parks in d_out[0, 16M)
    bf16* Ob   = (bf16*)((char*)d_out + 16777216);  // O parks in d_out[16M, 32M)

    convert_kernel<<<8192, 256, 0, stream>>>(x, xb);
    transpose_kernel<<<dim3(32, 32, 4), 256, 0, stream>>>(Wq, Wk, Wv, Wo, WT, WoT);
    gemm_kernel<0><<<dim3(24, 64), 256, 0, stream>>>(
        xb, WT, bq, bk, bv, nullptr, Qb, Kb, Vtb, nullptr, 3072, 1024);
    flash_kernel<<<dim3(64, 16), 256, 0, stream>>>(Qb, Kb, Vtb, Ob);
    gemm_kernel<1><<<dim3(8, 64), 256, 0, stream>>>(
        Ob, WoT, bo, nullptr, nullptr, x, nullptr, nullptr, nullptr, Tmpb, 1024, 1024);
    ln_kernel<<<8192, 256, 0, stream>>>(Tmpb, gamma, beta, out);
}